// Round 8
// baseline (1411.119 us; speedup 1.0000x reference)
//
#include <hip/hip_runtime.h>
#include <hip/hip_fp16.h>

typedef unsigned int uint;
typedef unsigned short ushort;
typedef unsigned long long ull;
typedef float f2v __attribute__((ext_vector_type(2)));

#define B 16
#define N 4096
#define S 1024          // NPOINT
#define K 32            // NSAMPLE
#define NPOS (B*S*K)    // 524288
#define NPAIR (NPOS/2)  // 262144

__device__ inline float h2f(ushort b) {
    __half h; *(ushort*)&h = b; return __half2float(h);
}
__device__ inline ushort f2h(float v) {
    __half h = __float2half(v); return *(ushort*)&h;
}

// packed f32 ops (VOP3P) — two IEEE rn f32 ops per instruction
__device__ inline f2v pk_sub(f2v a, f2v b) {
    f2v r; asm("v_pk_add_f32 %0, %1, %2 neg_lo:[0,1] neg_hi:[0,1]" : "=v"(r) : "v"(a), "v"(b)); return r;
}
__device__ inline f2v pk_mul(f2v a, f2v b) {
    f2v r; asm("v_pk_mul_f32 %0, %1, %2" : "=v"(r) : "v"(a), "v"(b)); return r;
}
__device__ inline f2v pk_add(f2v a, f2v b) {
    f2v r; asm("v_pk_add_f32 %0, %1, %2" : "=v"(r) : "v"(a), "v"(b)); return r;
}

// ---------------- FPS: one block (256 thr, 4 waves) per batch ----------------
// 16 pts/thread in registers (packed f2v). Inner loop: pk dist update + min.
// Argmax deferred: scalar max-tree (15) + descending first-index resolve,
// ONE u64 (dist,~j) pack, DPP wave reduce -> lane 63, atomicMax into 3-slot
// rotating LDS u64, ONE barrier per step.
__global__ __launch_bounds__(256) void fps_kernel(const float* __restrict__ xyz,
                                                  float* __restrict__ new_xyz) {
    const int b  = blockIdx.x;
    const int lt = threadIdx.x;          // 0..255
    __shared__ float4 lc[N];             // 64 KB
    __shared__ ull slot[3];

    const float* xb = xyz + (size_t)b * N * 3;
    f2v px[8], py[8], pz[8], d2[8];
    #pragma unroll
    for (int p = 0; p < 16; ++p) {
        const int j = lt + (p << 8);
        float x = xb[j*3+0], y = xb[j*3+1], z = xb[j*3+2];
        lc[j] = make_float4(x, y, z, 0.f);
        px[p >> 1][p & 1] = x;
        py[p >> 1][p & 1] = y;
        pz[p >> 1][p & 1] = z;
        d2[p >> 1][p & 1] = 1e10f;
    }
    if (lt < 3) slot[lt] = 0ull;
    __syncthreads();

    float4 c0 = lc[0];
    float cx = c0.x, cy = c0.y, cz = c0.z;
    float* outb = new_xyz + (size_t)b * S * 3;

    int cur = 0;
    for (int s = 0; s < S; ++s) {
        if (lt == 0) { outb[s*3+0] = cx; outb[s*3+1] = cy; outb[s*3+2] = cz; }

        const f2v c2x = {cx, cx}, c2y = {cy, cy}, c2z = {cz, cz};
        #pragma unroll
        for (int q = 0; q < 8; ++q) {
            f2v dx = pk_sub(px[q], c2x);
            f2v dy = pk_sub(py[q], c2y);
            f2v dz = pk_sub(pz[q], c2z);
            f2v ss = pk_add(pk_add(pk_mul(dx, dx), pk_mul(dy, dy)), pk_mul(dz, dz));
            d2[q][0] = fminf(d2[q][0], ss[0]);
            d2[q][1] = fminf(d2[q][1], ss[1]);
        }
        // scalar max tree over 16
        float m01 = fmaxf(d2[0][0], d2[0][1]), m23 = fmaxf(d2[1][0], d2[1][1]);
        float m45 = fmaxf(d2[2][0], d2[2][1]), m67 = fmaxf(d2[3][0], d2[3][1]);
        float m89 = fmaxf(d2[4][0], d2[4][1]), mab = fmaxf(d2[5][0], d2[5][1]);
        float mcd = fmaxf(d2[6][0], d2[6][1]), mef = fmaxf(d2[7][0], d2[7][1]);
        float m = fmaxf(fmaxf(fmaxf(m01, m23), fmaxf(m45, m67)),
                        fmaxf(fmaxf(m89, mab), fmaxf(mcd, mef)));
        // first-index resolve (descending -> smallest p wins ties)
        int cand = 0;
        #pragma unroll
        for (int p = 15; p >= 0; --p)
            if (d2[p >> 1][p & 1] >= m) cand = p;
        ull best = ((ull)__float_as_uint(m) << 32) |
                   (ull)(uint)(~(uint)(lt + (cand << 8)));

        // DPP wave-64 max reduction -> lane 63 (VALU pipe)
        {
            uint hi = (uint)(best >> 32), lo = (uint)best;
            #define FPS_DPP(CTRL) { \
                uint h2 = (uint)__builtin_amdgcn_update_dpp((int)hi, (int)hi, CTRL, 0xF, 0xF, false); \
                uint l2 = (uint)__builtin_amdgcn_update_dpp((int)lo, (int)lo, CTRL, 0xF, 0xF, false); \
                ull o = ((ull)h2 << 32) | (ull)l2; \
                if (o > best) { best = o; hi = h2; lo = l2; } }
            FPS_DPP(0x111)   // row_shr:1
            FPS_DPP(0x112)   // row_shr:2
            FPS_DPP(0x114)   // row_shr:4
            FPS_DPP(0x118)   // row_shr:8
            FPS_DPP(0x142)   // row_bcast:15
            FPS_DPP(0x143)   // row_bcast:31
            #undef FPS_DPP
        }
        if ((lt & 63) == 63) atomicMax(&slot[cur], best);
        int nxt = cur + 1; if (nxt == 3) nxt = 0;
        if (lt == 0) slot[nxt] = 0ull;   // slot last read 2 barriers ago (safe)
        __syncthreads();
        ull pk = slot[cur];
        int last = (int)(~(uint)pk);     // lo32 = ~j exactly
        float4 c4 = lc[last];
        cx = c4.x; cy = c4.y; cz = c4.z;
        cur = nxt;
    }
}

// ---- fused ball query (blocks 0..4095) + feature transpose (4096..5119) ----
__global__ __launch_bounds__(256) void ballq_tr_kernel(const float* __restrict__ xyz,
                                                       const float* __restrict__ new_xyz,
                                                       int* __restrict__ idx,
                                                       const float* __restrict__ feat,
                                                       float* __restrict__ featT) {
    __shared__ float tile[64][65];
    if (blockIdx.x >= 4096) {
        // ---------- transpose path: (B,64,N) -> (B,N,64) ----------
        const int tb = blockIdx.x - 4096;     // 0..1023
        const int b  = tb >> 6;
        const int n0 = (tb & 63) << 6;
        const int t  = threadIdx.x;
        const int tn = t & 63, r = t >> 6;
        for (int c = r; c < 64; c += 4)
            tile[c][tn] = feat[((size_t)b*64 + c)*N + n0 + tn];
        __syncthreads();
        for (int n = r; n < 64; n += 4)
            featT[((size_t)b*N + n0 + n)*64 + tn] = tile[tn][n];
        return;
    }
    // ---------- ball query: one wave per center (16384 waves total) ----------
    const int wid  = (blockIdx.x * 256 + threadIdx.x) >> 6;   // center id < 16384
    const int lane = threadIdx.x & 63;
    const int b = wid >> 10;
    const float* xb = xyz + (size_t)b * N * 3;
    const float cx = new_xyz[(size_t)wid*3+0];
    const float cy = new_xyz[(size_t)wid*3+1];
    const float cz = new_xyz[(size_t)wid*3+2];
    int* ob = idx + (size_t)wid * K;

    const float R2 = 0.04f;  // float32(0.2*0.2) per JAX weak-type demotion
    int total = 0;
    int first = 0;
    bool gotfirst = false;
    for (int c0 = 0; c0 < N; c0 += 64) {
        const int j = c0 + lane;
        float dx = cx - xb[j*3+0];
        float dy = cy - xb[j*3+1];
        float dz = cz - xb[j*3+2];
        float d2 = __fadd_rn(__fadd_rn(__fmul_rn(dx,dx), __fmul_rn(dy,dy)), __fmul_rn(dz,dz));
        bool inr = d2 < R2;
        unsigned long long bal = __ballot(inr);
        if (bal) {
            if (!gotfirst) { first = c0 + __builtin_ctzll(bal); gotfirst = true; }
            int rank = __popcll(bal & ((1ull << lane) - 1ull));
            int pos = total + rank;
            if (inr && pos < K) ob[pos] = j;
            total += __popcll(bal);
            if (total >= K) break;
        }
    }
    for (int p2 = total + lane; p2 < K; p2 += 64) ob[p2] = first;
}

// ---------------- conv0: LDS-tiled GEMM, 128 positions x 64 outputs, K=68 ----
__global__ __launch_bounds__(256) void conv0_kernel(const float* __restrict__ xyz,
                                                    const float* __restrict__ new_xyz,
                                                    const float* __restrict__ featT,
                                                    const int* __restrict__ idx,
                                                    const float* __restrict__ w0,
                                                    const float* __restrict__ b0,
                                                    ushort* __restrict__ x0) {
    __shared__ float xt[68][128];   // 34.8 KB
    __shared__ float wt[68][64];    // 17.4 KB
    const int t  = threadIdx.x;
    const int p0 = blockIdx.x * 128;

    for (int i = t; i < 68*64; i += 256) {
        const int k = i >> 6, o = i & 63;
        wt[k][o] = (k < 67) ? w0[(size_t)o*67 + k] : 0.f;
    }
    if (t < 128) {
        const int p  = p0 + t;
        const int bs = p >> 5;
        const int b  = p >> 15;
        const int j  = idx[p];
        const float* xp = xyz + ((size_t)b*N + (size_t)j)*3;
        xt[0][t] = xp[0] - new_xyz[(size_t)bs*3+0];
        xt[1][t] = xp[1] - new_xyz[(size_t)bs*3+1];
        xt[2][t] = xp[2] - new_xyz[(size_t)bs*3+2];
    } else {
        xt[67][t-128] = 0.f;
    }
    #pragma unroll
    for (int r = 0; r < 8; ++r) {
        const int i = t + (r << 8);
        const int q = i >> 7;           // 0..15
        const int p = i & 127;
        const int gp = p0 + p;
        const int b  = gp >> 15;
        const int j  = idx[gp];
        const float4 v = *(const float4*)(featT + ((((size_t)b*N + j) << 6) + (q << 2)));
        xt[3 + 4*q + 0][p] = v.x;
        xt[3 + 4*q + 1][p] = v.y;
        xt[3 + 4*q + 2][p] = v.z;
        xt[3 + 4*q + 3][p] = v.w;
    }
    __syncthreads();

    const int po = t >> 3;   // 0..31 -> positions po*4 .. po*4+3
    const int og = t & 7;    // outputs og*8 .. og*8+7
    float a[4][8];
    #pragma unroll
    for (int i = 0; i < 8; ++i) {
        const float bv = b0[og*8 + i];
        a[0][i] = bv; a[1][i] = bv; a[2][i] = bv; a[3][i] = bv;
    }
    #pragma unroll 2
    for (int k = 0; k < 68; ++k) {
        const float4 xv = *(const float4*)&xt[k][po*4];
        float w[8];
        *(float4*)&w[0] = *(const float4*)&wt[k][og*8];
        *(float4*)&w[4] = *(const float4*)&wt[k][og*8+4];
        #pragma unroll
        for (int i = 0; i < 8; ++i) {
            a[0][i] = fmaf(w[i], xv.x, a[0][i]);
            a[1][i] = fmaf(w[i], xv.y, a[1][i]);
            a[2][i] = fmaf(w[i], xv.z, a[2][i]);
            a[3][i] = fmaf(w[i], xv.w, a[3][i]);
        }
    }
    #pragma unroll
    for (int i = 0; i < 8; ++i) {
        const int o = og*8 + i;
        uint2 wd;
        wd.x = (uint)f2h(a[0][i]) | ((uint)f2h(a[1][i]) << 16);
        wd.y = (uint)f2h(a[2][i]) | ((uint)f2h(a[3][i]) << 16);
        *(uint2*)(x0 + (size_t)o*NPOS + p0 + po*4) = wd;
    }
}

// ---------------- per-channel sum / sumsq (C=64 layout, stride 64) ----------------
__global__ __launch_bounds__(256) void stats_kernel(const ushort* __restrict__ x,
                                                    float* __restrict__ st) {
    const int c = blockIdx.y;   // 0..63
    const uint2* xr = (const uint2*)(x + (size_t)c * NPOS);
    const int t = blockIdx.x * 256 + threadIdx.x;   // 0..8191
    float s = 0.f, q = 0.f;
    #pragma unroll
    for (int i = 0; i < 16; ++i) {
        uint2 u = xr[(size_t)i*8192 + t];
        float v0 = h2f((ushort)(u.x & 0xffff));
        float v1 = h2f((ushort)(u.x >> 16));
        float v2 = h2f((ushort)(u.y & 0xffff));
        float v3 = h2f((ushort)(u.y >> 16));
        s += v0 + v1 + v2 + v3;
        q += v0*v0 + v1*v1 + v2*v2 + v3*v3;
    }
    #pragma unroll
    for (int off = 32; off; off >>= 1) { s += __shfl_xor(s, off); q += __shfl_xor(q, off); }
    __shared__ float ls[4], lq[4];
    const int w = threadIdx.x >> 6;
    if ((threadIdx.x & 63) == 0) { ls[w] = s; lq[w] = q; }
    __syncthreads();
    if (threadIdx.x == 0) {
        s = ls[0]+ls[1]+ls[2]+ls[3];
        q = lq[0]+lq[1]+lq[2]+lq[3];
        atomicAdd(&st[c], s);
        atomicAdd(&st[64+c], q);
    }
}

// ---------------- fold BN into scale/shift (C=64) ----------------
__global__ void finalize_kernel(float* st, const float* __restrict__ g,
                                const float* __restrict__ be) {
    const int c = threadIdx.x;
    if (c < 64) {
        const float invn = 1.0f / (float)NPOS;
        float mean = st[c] * invn;
        float var  = st[64+c] * invn - mean*mean;
        float inv  = 1.0f / sqrtf(var + 1e-5f);
        float sc   = g[c] * inv;
        st[128+c] = sc;
        st[192+c] = fmaf(-mean, sc, be[c]);
    }
}

// ---------------- middle conv: normalize(prev)+relu then 64->64 ----------------
__global__ __launch_bounds__(256) void conv_mid_kernel(const ushort* __restrict__ xin,
                                                       const float* __restrict__ st,   // prev layer stats
                                                       const float* __restrict__ w,
                                                       const float* __restrict__ bias,
                                                       ushort* __restrict__ xout,
                                                       int wbase) {
    const int pp = blockIdx.x * 256 + threadIdx.x;   // pair index < NPAIR
    const float* scale = st + 128;
    const float* shift = st + 192;
    float a0[64], a1[64];
    #pragma unroll
    for (int o = 0; o < 64; ++o) { a0[o] = bias[wbase+o]; a1[o] = a0[o]; }
    const uint* xr = (const uint*)xin;
    #pragma unroll 4
    for (int c = 0; c < 64; ++c) {
        uint u = xr[(size_t)c * NPAIR + pp];
        float v0 = h2f((ushort)(u & 0xffff));
        float v1 = h2f((ushort)(u >> 16));
        float sc = scale[c], sh = shift[c];
        v0 = fmaxf(0.0f, fmaf(v0, sc, sh));
        v1 = fmaxf(0.0f, fmaf(v1, sc, sh));
        const float* wr = w + (size_t)wbase * 64 + c;
        #pragma unroll
        for (int o = 0; o < 64; ++o) {
            float wv = wr[o*64];
            a0[o] = fmaf(wv, v0, a0[o]);
            a1[o] = fmaf(wv, v1, a1[o]);
        }
    }
    uint* orow = (uint*)xout;
    #pragma unroll
    for (int o = 0; o < 64; ++o) {
        uint wd = (uint)f2h(a0[o]) | ((uint)f2h(a1[o]) << 16);
        orow[(size_t)o * NPAIR + pp] = wd;
    }
}

// ---------------- max-pool over K with BN+relu (64-channel half) ----------------
__global__ __launch_bounds__(256) void maxpool_kernel(const ushort* __restrict__ xh,
                                                      const float* __restrict__ st,   // this half's stats
                                                      float* __restrict__ out,
                                                      int cbase) {
    const int gid = blockIdx.x * 256 + threadIdx.x;   // < 64*16384
    const int c  = gid >> 14;       // 0..63 local channel
    const int bs = gid & 16383;
    const float sc = st[128 + c], sh = st[192 + c];
    const uint* xr = (const uint*)(xh + (size_t)c * NPOS + (size_t)bs * K);
    float m = -3.4e38f;
    #pragma unroll
    for (int i = 0; i < 16; ++i) {
        uint u = xr[i];
        m = fmaxf(m, fmaf(h2f((ushort)(u & 0xffff)), sc, sh));
        m = fmaxf(m, fmaf(h2f((ushort)(u >> 16)),    sc, sh));
    }
    m = fmaxf(m, 0.0f);   // relu(max) == max(relu) (monotone)
    const int b = bs >> 10, s = bs & 1023;
    out[((size_t)b*128 + cbase + c)*1024 + s] = m;
}

extern "C" void kernel_launch(void* const* d_in, const int* in_sizes, int n_in,
                              void* d_out, int out_size, void* d_ws, size_t ws_size,
                              hipStream_t stream) {
    const float* xyz      = (const float*)d_in[0];
    const float* features = (const float*)d_in[1];
    const float* w0 = (const float*)d_in[2];
    const float* b0 = (const float*)d_in[3];
    const float* g0 = (const float*)d_in[4];
    const float* be0= (const float*)d_in[5];
    const float* w1 = (const float*)d_in[6];
    const float* b1 = (const float*)d_in[7];
    const float* g1 = (const float*)d_in[8];
    const float* be1= (const float*)d_in[9];
    const float* w2 = (const float*)d_in[10];
    const float* b2 = (const float*)d_in[11];
    const float* g2 = (const float*)d_in[12];
    const float* be2= (const float*)d_in[13];

    float* out      = (float*)d_out;
    float* new_xyz  = out;              // (B,S,3)
    float* new_feat = out + (size_t)B*S*3;

    char* ws = (char*)d_ws;
    int*    idx   = (int*)ws;
    float*  featT = (float*)(ws + (2u<<20));
    float*  stats = (float*)(ws + (18u<<20));
    ushort* x0    = (ushort*)(ws + (18u<<20) + (1u<<16));
    ushort* x1    = x0 + (size_t)64 * NPOS;       // +64MB
    ushort* xh    = x0;                           // layer-2 half buffer aliases x0
    float* st0  = stats;            // C=64: sum,sumsq,scale,shift
    float* st1  = stats + 256;
    float* st2a = stats + 512;
    float* st2b = stats + 768;

    hipMemsetAsync(stats, 0, 1024 * sizeof(float), stream);

    fps_kernel<<<B, 256, 0, stream>>>(xyz, new_xyz);
    ballq_tr_kernel<<<4096 + 1024, 256, 0, stream>>>(xyz, new_xyz, idx, features, featT);
    conv0_kernel<<<NPOS/128, 256, 0, stream>>>(xyz, new_xyz, featT, idx, w0, b0, x0);

    stats_kernel<<<dim3(32, 64), 256, 0, stream>>>(x0, st0);
    finalize_kernel<<<1, 64, 0, stream>>>(st0, g0, be0);
    conv_mid_kernel<<<NPAIR/256, 256, 0, stream>>>(x0, st0, w1, b1, x1, 0);

    stats_kernel<<<dim3(32, 64), 256, 0, stream>>>(x1, st1);
    finalize_kernel<<<1, 64, 0, stream>>>(st1, g1, be1);

    // layer 2, half 0 (output channels 0..63) — xh aliases x0 (dead now)
    conv_mid_kernel<<<NPAIR/256, 256, 0, stream>>>(x1, st1, w2, b2, xh, 0);
    stats_kernel<<<dim3(32, 64), 256, 0, stream>>>(xh, st2a);
    finalize_kernel<<<1, 64, 0, stream>>>(st2a, g2, be2);
    maxpool_kernel<<<(64*B*S)/256, 256, 0, stream>>>(xh, st2a, new_feat, 0);

    // layer 2, half 1 (output channels 64..127)
    conv_mid_kernel<<<NPAIR/256, 256, 0, stream>>>(x1, st1, w2, b2, xh, 64);
    stats_kernel<<<dim3(32, 64), 256, 0, stream>>>(xh, st2b);
    finalize_kernel<<<1, 64, 0, stream>>>(st2b, g2 + 64, be2 + 64);
    maxpool_kernel<<<(64*B*S)/256, 256, 0, stream>>>(xh, st2b, new_feat, 64);
}

// Round 10
// 1399.424 us; speedup vs baseline: 1.0084x; 1.0084x over previous
//
#include <hip/hip_runtime.h>
#include <hip/hip_fp16.h>

typedef unsigned int uint;
typedef unsigned short ushort;
typedef unsigned long long ull;
typedef float f2v __attribute__((ext_vector_type(2)));

#define B 16
#define N 4096
#define S 1024          // NPOINT
#define K 32            // NSAMPLE
#define NPOS (B*S*K)    // 524288
#define NPAIR (NPOS/2)  // 262144

__device__ inline float h2f(ushort b) {
    __half h; *(ushort*)&h = b; return __half2float(h);
}
__device__ inline ushort f2h(float v) {
    __half h = __float2half(v); return *(ushort*)&h;
}

// packed f32 ops (VOP3P) — two IEEE rn f32 ops per instruction
__device__ inline f2v pk_sub(f2v a, f2v b) {
    f2v r; asm("v_pk_add_f32 %0, %1, %2 neg_lo:[0,1] neg_hi:[0,1]" : "=v"(r) : "v"(a), "v"(b)); return r;
}
__device__ inline f2v pk_mul(f2v a, f2v b) {
    f2v r; asm("v_pk_mul_f32 %0, %1, %2" : "=v"(r) : "v"(a), "v"(b)); return r;
}
__device__ inline f2v pk_add(f2v a, f2v b) {
    f2v r; asm("v_pk_add_f32 %0, %1, %2" : "=v"(r) : "v"(a), "v"(b)); return r;
}

// ---- fused FPS (blocks 0..15, 512 thr) + transpose (blocks 16..527) ----
// FPS: 8 pts/thread packed f2v; deferred argmax (max-tree + descending
// first-index resolve); DPP wave reduce -> lane 63; NO atomics: per-wave
// ds_write into double-buffered rv[2][8], ONE barrier, all-thread broadcast
// read + 7-op u64 max; centroid via lc[last] broadcast read.
__global__ __launch_bounds__(512) void fps_tr_kernel(const float* __restrict__ xyz,
                                                     float* __restrict__ new_xyz,
                                                     const float* __restrict__ feat,
                                                     float* __restrict__ featT) {
    __shared__ float4 lc[N];      // 64 KB
    __shared__ ull rv[2][8];
    const int lt = threadIdx.x;   // 0..511

    if (blockIdx.x >= 16) {
        // ---------- transpose path: (B,64,N) -> (B,N,64) ----------
        float* tile = (float*)lc;             // 2 * 64*65 floats = 33 KB
        const int tb = blockIdx.x - 16;       // 0..511
        const int b  = tb >> 5;               // batch
        const int nb = (tb & 31) << 7;        // 128-col chunk
        const int h  = lt >> 8;               // half: 0/1
        const int tt = lt & 255;
        const int tn = tt & 63;
        const int r  = tt >> 6;               // 0..3
        float* mytile = tile + h * (64 * 65);
        const int n0 = nb + (h << 6);
        for (int c = r; c < 64; c += 4)
            mytile[c * 65 + tn] = feat[((size_t)b * 64 + c) * N + n0 + tn];
        __syncthreads();
        for (int n = r; n < 64; n += 4)
            featT[((size_t)b * N + n0 + n) * 64 + tn] = mytile[tn * 65 + n];
        return;
    }

    // ---------- FPS path ----------
    const int b = blockIdx.x;
    const float* xb = xyz + (size_t)b * N * 3;
    f2v px[4], py[4], pz[4], d2[4];
    #pragma unroll
    for (int p = 0; p < 8; ++p) {
        const int j = lt + (p << 9);
        float x = xb[j*3+0], y = xb[j*3+1], z = xb[j*3+2];
        lc[j] = make_float4(x, y, z, 0.f);
        px[p >> 1][p & 1] = x;
        py[p >> 1][p & 1] = y;
        pz[p >> 1][p & 1] = z;
        d2[p >> 1][p & 1] = 1e10f;
    }
    __syncthreads();

    float4 c0 = lc[0];
    float cx = c0.x, cy = c0.y, cz = c0.z;
    float* outb = new_xyz + (size_t)b * S * 3;

    int buf = 0;
    for (int s = 0; s < S; ++s) {
        if (lt == 0) { outb[s*3+0] = cx; outb[s*3+1] = cy; outb[s*3+2] = cz; }

        const f2v c2x = {cx, cx}, c2y = {cy, cy}, c2z = {cz, cz};
        #pragma unroll
        for (int q = 0; q < 4; ++q) {
            f2v dx = pk_sub(px[q], c2x);
            f2v dy = pk_sub(py[q], c2y);
            f2v dz = pk_sub(pz[q], c2z);
            f2v ss = pk_add(pk_add(pk_mul(dx, dx), pk_mul(dy, dy)), pk_mul(dz, dz));
            d2[q][0] = fminf(d2[q][0], ss[0]);
            d2[q][1] = fminf(d2[q][1], ss[1]);
        }
        // max tree over 8
        float m0 = fmaxf(d2[0][0], d2[0][1]);
        float m1 = fmaxf(d2[1][0], d2[1][1]);
        float m2 = fmaxf(d2[2][0], d2[2][1]);
        float m3 = fmaxf(d2[3][0], d2[3][1]);
        float m  = fmaxf(fmaxf(m0, m1), fmaxf(m2, m3));
        // first-index resolve (descending -> smallest p wins ties)
        int cand = 0;
        #pragma unroll
        for (int p = 7; p >= 0; --p)
            if (d2[p >> 1][p & 1] >= m) cand = p;
        ull best = ((ull)__float_as_uint(m) << 32) |
                   (ull)(uint)(~(uint)(lt + (cand << 9)));

        // DPP wave-64 max reduction -> lane 63 (VALU pipe)
        {
            uint hi = (uint)(best >> 32), lo = (uint)best;
            #define FPS_DPP(CTRL) { \
                uint h2 = (uint)__builtin_amdgcn_update_dpp((int)hi, (int)hi, CTRL, 0xF, 0xF, false); \
                uint l2 = (uint)__builtin_amdgcn_update_dpp((int)lo, (int)lo, CTRL, 0xF, 0xF, false); \
                ull o = ((ull)h2 << 32) | (ull)l2; \
                if (o > best) { best = o; hi = h2; lo = l2; } }
            FPS_DPP(0x111)   // row_shr:1
            FPS_DPP(0x112)   // row_shr:2
            FPS_DPP(0x114)   // row_shr:4
            FPS_DPP(0x118)   // row_shr:8
            FPS_DPP(0x142)   // row_bcast:15
            FPS_DPP(0x143)   // row_bcast:31
            #undef FPS_DPP
        }
        // cross-wave: lane 63 of each wave writes its u64; barrier; all
        // threads broadcast-read the 8 slots and max in registers.
        if ((lt & 63) == 63) rv[buf][lt >> 6] = best;
        __syncthreads();
        {
            const ull* rb = rv[buf];
            ull a0 = rb[0], a1 = rb[1], a2 = rb[2], a3 = rb[3];
            ull a4 = rb[4], a5 = rb[5], a6 = rb[6], a7 = rb[7];
            ull b0 = a0 > a1 ? a0 : a1;
            ull b1 = a2 > a3 ? a2 : a3;
            ull b2 = a4 > a5 ? a4 : a5;
            ull b3 = a6 > a7 ? a6 : a7;
            ull c0u = b0 > b1 ? b0 : b1;
            ull c1u = b2 > b3 ? b2 : b3;
            best = c0u > c1u ? c0u : c1u;
        }
        int last = (int)(~(uint)best);   // lo32 = ~j exactly
        float4 c4 = lc[last];
        cx = c4.x; cy = c4.y; cz = c4.z;
        buf ^= 1;
    }
}

// ---------------- ball query: one wave per center ----------------
__global__ __launch_bounds__(256) void ballq_kernel(const float* __restrict__ xyz,
                                                    const float* __restrict__ new_xyz,
                                                    int* __restrict__ idx) {
    const int wid  = (blockIdx.x * 256 + threadIdx.x) >> 6;   // center id
    const int lane = threadIdx.x & 63;
    const int b = wid >> 10;
    const float* xb = xyz + (size_t)b * N * 3;
    const float cx = new_xyz[(size_t)wid*3+0];
    const float cy = new_xyz[(size_t)wid*3+1];
    const float cz = new_xyz[(size_t)wid*3+2];
    int* ob = idx + (size_t)wid * K;

    const float R2 = 0.04f;  // float32(0.2*0.2) per JAX weak-type demotion
    int total = 0;
    int first = 0;
    bool gotfirst = false;
    for (int c0 = 0; c0 < N; c0 += 64) {
        const int j = c0 + lane;
        float dx = cx - xb[j*3+0];
        float dy = cy - xb[j*3+1];
        float dz = cz - xb[j*3+2];
        float d2 = __fadd_rn(__fadd_rn(__fmul_rn(dx,dx), __fmul_rn(dy,dy)), __fmul_rn(dz,dz));
        bool inr = d2 < R2;
        unsigned long long bal = __ballot(inr);
        if (bal) {
            if (!gotfirst) { first = c0 + __builtin_ctzll(bal); gotfirst = true; }
            int rank = __popcll(bal & ((1ull << lane) - 1ull));
            int pos = total + rank;
            if (inr && pos < K) ob[pos] = j;
            total += __popcll(bal);
            if (total >= K) break;
        }
    }
    for (int p2 = total + lane; p2 < K; p2 += 64) ob[p2] = first;
}

// ---------------- conv0: LDS-tiled GEMM, 128 positions x 64 outputs, K=68 ----
__global__ __launch_bounds__(256) void conv0_kernel(const float* __restrict__ xyz,
                                                    const float* __restrict__ new_xyz,
                                                    const float* __restrict__ featT,
                                                    const int* __restrict__ idx,
                                                    const float* __restrict__ w0,
                                                    const float* __restrict__ b0,
                                                    ushort* __restrict__ x0) {
    __shared__ float xt[68][128];   // 34.8 KB
    __shared__ float wt[68][64];    // 17.4 KB
    const int t  = threadIdx.x;
    const int p0 = blockIdx.x * 128;

    for (int i = t; i < 68*64; i += 256) {
        const int k = i >> 6, o = i & 63;
        wt[k][o] = (k < 67) ? w0[(size_t)o*67 + k] : 0.f;
    }
    if (t < 128) {
        const int p  = p0 + t;
        const int bs = p >> 5;
        const int b  = p >> 15;
        const int j  = idx[p];
        const float* xp = xyz + ((size_t)b*N + (size_t)j)*3;
        xt[0][t] = xp[0] - new_xyz[(size_t)bs*3+0];
        xt[1][t] = xp[1] - new_xyz[(size_t)bs*3+1];
        xt[2][t] = xp[2] - new_xyz[(size_t)bs*3+2];
    } else {
        xt[67][t-128] = 0.f;
    }
    #pragma unroll
    for (int r = 0; r < 8; ++r) {
        const int i = t + (r << 8);
        const int q = i >> 7;           // 0..15
        const int p = i & 127;
        const int gp = p0 + p;
        const int b  = gp >> 15;
        const int j  = idx[gp];
        const float4 v = *(const float4*)(featT + ((((size_t)b*N + j) << 6) + (q << 2)));
        xt[3 + 4*q + 0][p] = v.x;
        xt[3 + 4*q + 1][p] = v.y;
        xt[3 + 4*q + 2][p] = v.z;
        xt[3 + 4*q + 3][p] = v.w;
    }
    __syncthreads();

    const int po = t >> 3;   // 0..31 -> positions po*4 .. po*4+3
    const int og = t & 7;    // outputs og*8 .. og*8+7
    float a[4][8];
    #pragma unroll
    for (int i = 0; i < 8; ++i) {
        const float bv = b0[og*8 + i];
        a[0][i] = bv; a[1][i] = bv; a[2][i] = bv; a[3][i] = bv;
    }
    #pragma unroll 2
    for (int k = 0; k < 68; ++k) {
        const float4 xv = *(const float4*)&xt[k][po*4];
        float w[8];
        *(float4*)&w[0] = *(const float4*)&wt[k][og*8];
        *(float4*)&w[4] = *(const float4*)&wt[k][og*8+4];
        #pragma unroll
        for (int i = 0; i < 8; ++i) {
            a[0][i] = fmaf(w[i], xv.x, a[0][i]);
            a[1][i] = fmaf(w[i], xv.y, a[1][i]);
            a[2][i] = fmaf(w[i], xv.z, a[2][i]);
            a[3][i] = fmaf(w[i], xv.w, a[3][i]);
        }
    }
    #pragma unroll
    for (int i = 0; i < 8; ++i) {
        const int o = og*8 + i;
        uint2 wd;
        wd.x = (uint)f2h(a[0][i]) | ((uint)f2h(a[1][i]) << 16);
        wd.y = (uint)f2h(a[2][i]) | ((uint)f2h(a[3][i]) << 16);
        *(uint2*)(x0 + (size_t)o*NPOS + p0 + po*4) = wd;
    }
}

// ---------------- per-channel sum / sumsq (C=64 layout, stride 64) ----------------
__global__ __launch_bounds__(256) void stats_kernel(const ushort* __restrict__ x,
                                                    float* __restrict__ st) {
    const int c = blockIdx.y;   // 0..63
    const uint2* xr = (const uint2*)(x + (size_t)c * NPOS);
    const int t = blockIdx.x * 256 + threadIdx.x;   // 0..8191
    float s = 0.f, q = 0.f;
    #pragma unroll
    for (int i = 0; i < 16; ++i) {
        uint2 u = xr[(size_t)i*8192 + t];
        float v0 = h2f((ushort)(u.x & 0xffff));
        float v1 = h2f((ushort)(u.x >> 16));
        float v2 = h2f((ushort)(u.y & 0xffff));
        float v3 = h2f((ushort)(u.y >> 16));
        s += v0 + v1 + v2 + v3;
        q += v0*v0 + v1*v1 + v2*v2 + v3*v3;
    }
    #pragma unroll
    for (int off = 32; off; off >>= 1) { s += __shfl_xor(s, off); q += __shfl_xor(q, off); }
    __shared__ float ls[4], lq[4];
    const int w = threadIdx.x >> 6;
    if ((threadIdx.x & 63) == 0) { ls[w] = s; lq[w] = q; }
    __syncthreads();
    if (threadIdx.x == 0) {
        s = ls[0]+ls[1]+ls[2]+ls[3];
        q = lq[0]+lq[1]+lq[2]+lq[3];
        atomicAdd(&st[c], s);
        atomicAdd(&st[64+c], q);
    }
}

// ---------------- fold BN into scale/shift (C=64) ----------------
__global__ void finalize_kernel(float* st, const float* __restrict__ g,
                                const float* __restrict__ be) {
    const int c = threadIdx.x;
    if (c < 64) {
        const float invn = 1.0f / (float)NPOS;
        float mean = st[c] * invn;
        float var  = st[64+c] * invn - mean*mean;
        float inv  = 1.0f / sqrtf(var + 1e-5f);
        float sc   = g[c] * inv;
        st[128+c] = sc;
        st[192+c] = fmaf(-mean, sc, be[c]);
    }
}

// ---------------- middle conv: normalize(prev)+relu then 64->64 ----------------
__global__ __launch_bounds__(256) void conv_mid_kernel(const ushort* __restrict__ xin,
                                                       const float* __restrict__ st,   // prev layer stats
                                                       const float* __restrict__ w,
                                                       const float* __restrict__ bias,
                                                       ushort* __restrict__ xout,
                                                       int wbase) {
    const int pp = blockIdx.x * 256 + threadIdx.x;   // pair index < NPAIR
    const float* scale = st + 128;
    const float* shift = st + 192;
    float a0[64], a1[64];
    #pragma unroll
    for (int o = 0; o < 64; ++o) { a0[o] = bias[wbase+o]; a1[o] = a0[o]; }
    const uint* xr = (const uint*)xin;
    #pragma unroll 4
    for (int c = 0; c < 64; ++c) {
        uint u = xr[(size_t)c * NPAIR + pp];
        float v0 = h2f((ushort)(u & 0xffff));
        float v1 = h2f((ushort)(u >> 16));
        float sc = scale[c], sh = shift[c];
        v0 = fmaxf(0.0f, fmaf(v0, sc, sh));
        v1 = fmaxf(0.0f, fmaf(v1, sc, sh));
        const float* wr = w + (size_t)wbase * 64 + c;
        #pragma unroll
        for (int o = 0; o < 64; ++o) {
            float wv = wr[o*64];
            a0[o] = fmaf(wv, v0, a0[o]);
            a1[o] = fmaf(wv, v1, a1[o]);
        }
    }
    uint* orow = (uint*)xout;
    #pragma unroll
    for (int o = 0; o < 64; ++o) {
        uint wd = (uint)f2h(a0[o]) | ((uint)f2h(a1[o]) << 16);
        orow[(size_t)o * NPAIR + pp] = wd;
    }
}

// ---------------- max-pool over K with BN+relu (64-channel half) ----------------
__global__ __launch_bounds__(256) void maxpool_kernel(const ushort* __restrict__ xh,
                                                      const float* __restrict__ st,   // this half's stats
                                                      float* __restrict__ out,
                                                      int cbase) {
    const int gid = blockIdx.x * 256 + threadIdx.x;   // < 64*16384
    const int c  = gid >> 14;       // 0..63 local channel
    const int bs = gid & 16383;
    const float sc = st[128 + c], sh = st[192 + c];
    const uint* xr = (const uint*)(xh + (size_t)c * NPOS + (size_t)bs * K);
    float m = -3.4e38f;
    #pragma unroll
    for (int i = 0; i < 16; ++i) {
        uint u = xr[i];
        m = fmaxf(m, fmaf(h2f((ushort)(u & 0xffff)), sc, sh));
        m = fmaxf(m, fmaf(h2f((ushort)(u >> 16)),    sc, sh));
    }
    m = fmaxf(m, 0.0f);   // relu(max) == max(relu) (monotone)
    const int b = bs >> 10, s = bs & 1023;
    out[((size_t)b*128 + cbase + c)*1024 + s] = m;
}

extern "C" void kernel_launch(void* const* d_in, const int* in_sizes, int n_in,
                              void* d_out, int out_size, void* d_ws, size_t ws_size,
                              hipStream_t stream) {
    const float* xyz      = (const float*)d_in[0];
    const float* features = (const float*)d_in[1];
    const float* w0 = (const float*)d_in[2];
    const float* b0 = (const float*)d_in[3];
    const float* g0 = (const float*)d_in[4];
    const float* be0= (const float*)d_in[5];
    const float* w1 = (const float*)d_in[6];
    const float* b1 = (const float*)d_in[7];
    const float* g1 = (const float*)d_in[8];
    const float* be1= (const float*)d_in[9];
    const float* w2 = (const float*)d_in[10];
    const float* b2 = (const float*)d_in[11];
    const float* g2 = (const float*)d_in[12];
    const float* be2= (const float*)d_in[13];

    float* out      = (float*)d_out;
    float* new_xyz  = out;              // (B,S,3)
    float* new_feat = out + (size_t)B*S*3;

    char* ws = (char*)d_ws;
    int*    idx   = (int*)ws;
    float*  featT = (float*)(ws + (2u<<20));
    float*  stats = (float*)(ws + (18u<<20));
    ushort* x0    = (ushort*)(ws + (18u<<20) + (1u<<16));
    ushort* x1    = x0 + (size_t)64 * NPOS;       // +64MB
    ushort* xh    = x0;                           // layer-2 half buffer aliases x0
    float* st0  = stats;            // C=64: sum,sumsq,scale,shift
    float* st1  = stats + 256;
    float* st2a = stats + 512;
    float* st2b = stats + 768;

    hipMemsetAsync(stats, 0, 1024 * sizeof(float), stream);

    fps_tr_kernel<<<16 + 512, 512, 0, stream>>>(xyz, new_xyz, features, featT);
    ballq_kernel<<<(B*S)/4, 256, 0, stream>>>(xyz, new_xyz, idx);
    conv0_kernel<<<NPOS/128, 256, 0, stream>>>(xyz, new_xyz, featT, idx, w0, b0, x0);

    stats_kernel<<<dim3(32, 64), 256, 0, stream>>>(x0, st0);
    finalize_kernel<<<1, 64, 0, stream>>>(st0, g0, be0);
    conv_mid_kernel<<<NPAIR/256, 256, 0, stream>>>(x0, st0, w1, b1, x1, 0);

    stats_kernel<<<dim3(32, 64), 256, 0, stream>>>(x1, st1);
    finalize_kernel<<<1, 64, 0, stream>>>(st1, g1, be1);

    // layer 2, half 0 (output channels 0..63) — xh aliases x0 (dead now)
    conv_mid_kernel<<<NPAIR/256, 256, 0, stream>>>(x1, st1, w2, b2, xh, 0);
    stats_kernel<<<dim3(32, 64), 256, 0, stream>>>(xh, st2a);
    finalize_kernel<<<1, 64, 0, stream>>>(st2a, g2, be2);
    maxpool_kernel<<<(64*B*S)/256, 256, 0, stream>>>(xh, st2a, new_feat, 0);

    // layer 2, half 1 (output channels 64..127)
    conv_mid_kernel<<<NPAIR/256, 256, 0, stream>>>(x1, st1, w2, b2, xh, 64);
    stats_kernel<<<dim3(32, 64), 256, 0, stream>>>(xh, st2b);
    finalize_kernel<<<1, 64, 0, stream>>>(st2b, g2 + 64, be2 + 64);
    maxpool_kernel<<<(64*B*S)/256, 256, 0, stream>>>(xh, st2b, new_feat, 64);
}